// Round 7
// baseline (135.667 us; speedup 1.0000x reference)
//
#include <hip/hip_runtime.h>

// multi_triples_lstm v21: 32x32x16 MFMA, 32 batches/wave, instruction diet.
// Law fitting ALL v14-v20 points: dur ∝ executed wave-instrs per CU
// (~2 cyc/instr/CU), type-independent (v16/v17 scale up linearly; v19's -2
// instrs = null; occupancy/barriers/code-size/WG-count all null).
// => cut instructions: 4 gate-tiles of 32x32x16 (h: 2 K-halves = 8 MFMA,
// x: K=16 exact = 4 MFMA) -> 12 MFMA per 32 batches vs 32 for 16x16 tiling;
// no zero-pad frags; loop overhead halved. Activation work conserved
// (16 units/lane, v18 chain algebra verbatim).
// Feedback permutation (32x32 C layout: col=lane&31, row=(reg&3)+8(reg>>2)
// +4hi): W rows permuted by swapping bits0,1 of row-block index => lane's h
// values ARE its next B-frag (k=8hi+j), pack order = identity. Barrier-free.
#define XSTRIDE 1040     // 65 x 16B: 32 t x 32B = 1024 + 16 pad
#define LDS_BYTES (32 * XSTRIDE)

typedef _Float16 f16x8 __attribute__((ext_vector_type(8)));
typedef __fp16   fp16x2 __attribute__((ext_vector_type(2)));
typedef float    f32x16 __attribute__((ext_vector_type(16)));
typedef float    f32x2 __attribute__((ext_vector_type(2)));

#define LOG2E     1.44269504088896f
#define TWO_LOG2E 2.88539008177793f

static __device__ __forceinline__ f16x8 cvt8(float4 a, float4 b, float s)
{
    f16x8 r;
    r[0]=(_Float16)(a.x*s); r[1]=(_Float16)(a.y*s);
    r[2]=(_Float16)(a.z*s); r[3]=(_Float16)(a.w*s);
    r[4]=(_Float16)(b.x*s); r[5]=(_Float16)(b.y*s);
    r[6]=(_Float16)(b.z*s); r[7]=(_Float16)(b.w*s);
    return r;
}

__global__ __launch_bounds__(64, 1)
void lstm_fused(const int* __restrict__ objs,
                const float* __restrict__ boxes,
                const int* __restrict__ preds,
                const int* __restrict__ subj,
                const float* __restrict__ obj_emb,
                const float* __restrict__ pred_emb,
                const float* __restrict__ W_ih,
                const float* __restrict__ W_hh,
                const float* __restrict__ b_ih,
                const float* __restrict__ b_hh,
                const float* __restrict__ fc2_W,
                const float* __restrict__ fc2_b,
                float* __restrict__ out)
{
    extern __shared__ char smem[];
    const int lane = threadIdx.x;        // 0..63
    const int hi   = lane >> 5;          // 0..1: K-half / row-half select
    const int col  = lane & 31;          // batch column (B) / A row (M)

    // ---- stage x features (fp16) for this wave's 32 batches ----
    {
        const int b = lane >> 1;         // 0..31
        const int j = lane & 1;
        const long gb = (long)blockIdx.x * 32 + b;
        const int* orow = objs + gb * 32;
        const int* prow = preds + gb * 32;
        const int* srow = subj + gb * 32;
        const float* brow = boxes + gb * 128;
        char* xrow = smem + b * XSTRIDE;
        #pragma unroll
        for (int tt = 0; tt < 16; ++tt) {
            int t = j + tt * 2;
            int o = orow[t], p = prow[t], sv = srow[t];
            const float* eo = obj_emb + o * 5;
            const float* ep = pred_emb + p * 5;
            float4 bx = *(const float4*)(brow + t * 4);
            f16x8 lo8, hi8;
            lo8[0]=(_Float16)eo[0]; lo8[1]=(_Float16)eo[1]; lo8[2]=(_Float16)eo[2];
            lo8[3]=(_Float16)eo[3]; lo8[4]=(_Float16)eo[4];
            lo8[5]=(_Float16)ep[0]; lo8[6]=(_Float16)ep[1]; lo8[7]=(_Float16)ep[2];
            hi8[0]=(_Float16)ep[3]; hi8[1]=(_Float16)ep[4];
            hi8[2]=(_Float16)(sv==0 ? 1.0f : 0.0f);
            hi8[3]=(_Float16)(sv==1 ? 1.0f : 0.0f);
            hi8[4]=(_Float16)bx.x; hi8[5]=(_Float16)bx.y;
            hi8[6]=(_Float16)bx.z; hi8[7]=(_Float16)bx.w;
            *(f16x8*)(xrow + t * 32)      = lo8;
            *(f16x8*)(xrow + t * 32 + 16) = hi8;
        }
    }

    // ---- W fragments + bias ----
    // A row m=col holds canonical unit u(m): swap bits0,1 of block index.
    const int bb = col >> 2;
    const int bp = (bb & 4) | ((bb & 1) << 1) | ((bb >> 1) & 1);
    const int up = (col & 3) | (bp << 2);
    // C reg -> unit: reg<8 -> 8hi+reg ; reg>=8 -> 16+8hi+(reg-8)
    f16x8 WH0[4], WH1[4], WX[4];
    f32x16 bias[4];
    #pragma unroll
    for (int a = 0; a < 4; ++a) {
        const float scale = (a == 2) ? TWO_LOG2E : -LOG2E;
        const int n = a * 32 + up;
        const float* wh = W_hh + n * 32 + 8 * hi;
        WH0[a] = cvt8(*(const float4*)(wh),      *(const float4*)(wh + 4),  scale);
        WH1[a] = cvt8(*(const float4*)(wh + 16), *(const float4*)(wh + 20), scale);
        const float* wx = W_ih + n * 16 + 8 * hi;
        WX[a]  = cvt8(*(const float4*)(wx),      *(const float4*)(wx + 4),  scale);
        const float* bi = b_ih + a * 32;
        const float* bh = b_hh + a * 32;
        #pragma unroll
        for (int r = 0; r < 8; ++r)
            bias[a][r]     = (bi[8*hi + r]      + bh[8*hi + r])      * scale;
        #pragma unroll
        for (int r = 0; r < 8; ++r)
            bias[a][8 + r] = (bi[16 + 8*hi + r] + bh[16 + 8*hi + r]) * scale;
    }

    __syncthreads();   // staging visible

    // ---- recurrence: barrier-free, rolled ----
    int xaddr = col * XSTRIDE + hi * 16;
    f16x8 xfrag = *(const f16x8*)(smem + xaddr); xaddr += 32;
    f32x16 accp[4];
    #pragma unroll
    for (int a = 0; a < 4; ++a)
        accp[a] = __builtin_amdgcn_mfma_f32_32x32x16_f16(WX[a], xfrag, bias[a], 0, 0, 0);

    union u32x4 { int i[4]; f16x8 v; };
    u32x4 hB0, hB1;
    hB0.i[0]=0; hB0.i[1]=0; hB0.i[2]=0; hB0.i[3]=0;
    hB1.i[0]=0; hB1.i[1]=0; hB1.i[2]=0; hB1.i[3]=0;
    const f32x2 zz = {0.0f, 0.0f};
    f32x2 cst[8] = {zz, zz, zz, zz, zz, zz, zz, zz};
    f32x2 hv[8];
    const f32x2 one = {1.0f, 1.0f};

    #pragma unroll 1
    for (int t = 0; t < 32; ++t) {
        f32x16 acc[4];
        #pragma unroll
        for (int a = 0; a < 4; ++a) {
            f32x16 tmp = __builtin_amdgcn_mfma_f32_32x32x16_f16(WH0[a], hB0.v, accp[a], 0, 0, 0);
            acc[a]     = __builtin_amdgcn_mfma_f32_32x32x16_f16(WH1[a], hB1.v, tmp,     0, 0, 0);
        }

        f16x8 xn = *(const f16x8*)(smem + xaddr); xaddr += 32;

        // 8 chains; chain r -> regs 2r,2r+1 (units in B-pack identity order)
        u32x4 nb0, nb1;
        #pragma unroll
        for (int r = 0; r < 8; ++r) {
            const int r0 = 2 * r;
            f32x2 zi = {acc[0][r0], acc[0][r0+1]};
            f32x2 zf = {acc[1][r0], acc[1][r0+1]};
            f32x2 zg = {acc[2][r0], acc[2][r0+1]};
            f32x2 zo = {acc[3][r0], acc[3][r0+1]};
            f32x2 Ei = {__builtin_amdgcn_exp2f(zi.x), __builtin_amdgcn_exp2f(zi.y)};
            f32x2 Ef = {__builtin_amdgcn_exp2f(zf.x), __builtin_amdgcn_exp2f(zf.y)};
            f32x2 Eg = {__builtin_amdgcn_exp2f(zg.x), __builtin_amdgcn_exp2f(zg.y)};
            f32x2 Eo = {__builtin_amdgcn_exp2f(zo.x), __builtin_amdgcn_exp2f(zo.y)};
            f32x2 t1  = Ei + one;
            f32x2 dig = t1 * Eg + t1;                 // (1+Ei)(1+Eg)
            f32x2 tf  = Ef + one;
            f32x2 nn  = (Eg - one) * tf + cst[r] * dig;
            f32x2 den = tf * dig;
            f32x2 rde = {__builtin_amdgcn_rcpf(den.x), __builtin_amdgcn_rcpf(den.y)};
            f32x2 c   = nn * rde;
            cst[r] = c;
            f32x2 cl  = c * TWO_LOG2E;
            f32x2 Ec  = {__builtin_amdgcn_exp2f(cl.x), __builtin_amdgcn_exp2f(cl.y)};
            f32x2 to  = Eo + one;
            f32x2 dh  = to * Ec + to;                 // (1+Eo)(1+Ec)
            f32x2 rdh = {__builtin_amdgcn_rcpf(dh.x), __builtin_amdgcn_rcpf(dh.y)};
            hv[r] = (Ec - one) * rdh;
            union { fp16x2 h; int i; } pk;
            pk.h = __builtin_amdgcn_cvt_pkrtz(hv[r].x, hv[r].y);
            if (r < 4) nb0.i[r] = pk.i; else nb1.i[r - 4] = pk.i;
        }
        hB0 = nb0; hB1 = nb1;

        #pragma unroll
        for (int a = 0; a < 4; ++a)
            accp[a] = __builtin_amdgcn_mfma_f32_32x32x16_f16(WX[a], xn, bias[a], 0, 0, 0);
    }

    // ---- fc2 epilogue: per-lane partial over 16 units, shfl-combine ----
    float p[4];
    #pragma unroll
    for (int j = 0; j < 4; ++j) {
        const float* fw = fc2_W + j * 32;
        float s = 0.0f;
        #pragma unroll
        for (int r = 0; r < 4; ++r) {          // regs 0..7: units 8hi+2r, +1
            s += fw[8*hi + 2*r]     * hv[r].x;
            s += fw[8*hi + 2*r + 1] * hv[r].y;
        }
        #pragma unroll
        for (int r = 4; r < 8; ++r) {          // regs 8..15: units 16+8hi+...
            s += fw[16 + 8*hi + 2*(r-4)]     * hv[r].x;
            s += fw[16 + 8*hi + 2*(r-4) + 1] * hv[r].y;
        }
        p[j] = s;
    }
    #pragma unroll
    for (int j = 0; j < 4; ++j)
        p[j] += __shfl_xor(p[j], 32);
    if (lane < 32) {
        float4 o4;
        o4.x = fminf(fmaxf(p[0] + fc2_b[0], 0.0f), 1.0f);
        o4.y = fminf(fmaxf(p[1] + fc2_b[1], 0.0f), 1.0f);
        o4.z = fminf(fmaxf(p[2] + fc2_b[2], 0.0f), 1.0f);
        o4.w = fminf(fmaxf(p[3] + fc2_b[3], 0.0f), 1.0f);
        *(float4*)(out + ((long)blockIdx.x * 32 + col) * 4) = o4;
    }
}

extern "C" void kernel_launch(void* const* d_in, const int* in_sizes, int n_in,
                              void* d_out, int out_size, void* d_ws, size_t ws_size,
                              hipStream_t stream)
{
    // inputs: 0 objs(i32) 1 boxes(f32) 2 preds(i32) 3 subj(i32) 4 target(unused)
    //         5 obj_emb 6 pred_emb 7 W_ih 8 W_hh 9 b_ih 10 b_hh 11 fc2_W 12 fc2_b
    lstm_fused<<<1024, 64, LDS_BYTES, stream>>>(
        (const int*)d_in[0], (const float*)d_in[1], (const int*)d_in[2],
        (const int*)d_in[3],
        (const float*)d_in[5], (const float*)d_in[6],
        (const float*)d_in[7], (const float*)d_in[8],
        (const float*)d_in[9], (const float*)d_in[10],
        (const float*)d_in[11], (const float*)d_in[12],
        (float*)d_out);
}